// Round 1
// baseline (672.993 us; speedup 1.0000x reference)
//
#include <hip/hip_runtime.h>

#define S_LEN 2048
#define QKV_N 4096
#define SCALE_Q 0.08838834764831845f

typedef __attribute__((ext_vector_type(8))) short short8;
typedef __attribute__((ext_vector_type(4))) float f32x4;
typedef __attribute__((ext_vector_type(4))) float floatv4;
typedef __attribute__((ext_vector_type(4))) unsigned short ushortv4;

__device__ __forceinline__ float bf2f(unsigned short u) {
  union { unsigned u; float f; } x; x.u = ((unsigned)u) << 16; return x.f;
}
__device__ __forceinline__ unsigned short f2bf(float f) {
  union { float f; unsigned u; } x; x.f = f;
  unsigned r = x.u + 0x7fffu + ((x.u >> 16) & 1u);
  return (unsigned short)(r >> 16);
}

typedef const unsigned int __attribute__((address_space(1)))* gas1_t;
typedef unsigned int __attribute__((address_space(3)))* las3_t;
#define GLL16(g, l) __builtin_amdgcn_global_load_lds((gas1_t)(const void*)(g), (las3_t)(void*)(l), 16, 0, 0)

// ---------------- f32 -> bf16 convert (vectorized) ----------------
__global__ __launch_bounds__(256) void k_cvt(const float* __restrict__ in,
                                             unsigned short* __restrict__ out, int n4) {
  int i = blockIdx.x * 256 + threadIdx.x;
  if (i >= n4) return;
  floatv4 v = ((const floatv4*)in)[i];
  ushortv4 o;
  o[0] = f2bf(v[0]); o[1] = f2bf(v[1]); o[2] = f2bf(v[2]); o[3] = f2bf(v[3]);
  ((ushortv4*)out)[i] = o;
}

// ---------------- transpose + convert: in[R][C] f32 -> out[C][R] bf16 ----------------
__global__ __launch_bounds__(256) void k_transpose_cvt(const float* __restrict__ in,
                                                       unsigned short* __restrict__ out,
                                                       int R, int C) {
  __shared__ float t[64][65];
  int bx = blockIdx.x;  // over C/64
  int by = blockIdx.y;  // over R/64
#pragma unroll
  for (int i = 0; i < 16; ++i) {
    int idx = threadIdx.x + i * 256;
    int r = idx >> 6, c = idx & 63;
    t[r][c] = in[(size_t)(by * 64 + r) * C + bx * 64 + c];
  }
  __syncthreads();
#pragma unroll
  for (int i = 0; i < 16; ++i) {
    int idx = threadIdx.x + i * 256;
    int r = idx >> 6, c = idx & 63;
    out[(size_t)(bx * 64 + r) * R + by * 64 + c] = f2bf(t[c][r]);
  }
}

// ---------------- 128x128x(BK=64) bf16 GEMM, C = A * BT^T ----------------
// A [M][K] row-major bf16, BT [N][K] row-major bf16 (i.e. B transposed).
// LDS XOR-swizzled (st-16B within 128B rows); staged via global_load_lds with
// inverse-swizzled global source (guide rule #21).
template <int OUT_BF16>
__global__ __launch_bounds__(256) void k_gemm(const unsigned short* __restrict__ A,
                                              const unsigned short* __restrict__ BT,
                                              void* __restrict__ Cout,
                                              int M, int N, int K) {
  const int lane = threadIdx.x & 63;
  const int wid = threadIdx.x >> 6;
  const int wr = wid >> 1, wc = wid & 1;
  const int lr = lane & 15, lg = lane >> 4;
  const int row0 = blockIdx.y * 128, col0 = blockIdx.x * 128;

  __shared__ __align__(16) unsigned short As[128 * 64];
  __shared__ __align__(16) unsigned short Bs[128 * 64];

  f32x4 acc[4][4];
#pragma unroll
  for (int m = 0; m < 4; ++m)
#pragma unroll
    for (int n = 0; n < 4; ++n) acc[m][n] = (f32x4){0.f, 0.f, 0.f, 0.f};

  size_t aoff[4], boff[4];
  int ldsoff[4];
#pragma unroll
  for (int i = 0; i < 4; ++i) {
    int c = threadIdx.x + i * 256;   // 16B chunk id, 0..1023
    int r = c >> 3, sb = c & 7;      // tile row, chunk-in-row
    int cs = (sb ^ (r & 7)) * 8;     // inverse-swizzled source element offset
    aoff[i] = (size_t)(row0 + r) * K + cs;
    boff[i] = (size_t)(col0 + r) * K + cs;
    ldsoff[i] = c * 16;
  }

  for (int k0 = 0; k0 < K; k0 += 64) {
    __syncthreads();
#pragma unroll
    for (int i = 0; i < 4; ++i) {
      GLL16(A + aoff[i] + k0, (char*)As + ldsoff[i]);
      GLL16(BT + boff[i] + k0, (char*)Bs + ldsoff[i]);
    }
    __syncthreads();
#pragma unroll
    for (int kk = 0; kk < 2; ++kk) {
      short8 af[4], bf[4];
#pragma unroll
      for (int m = 0; m < 4; ++m) {
        int rA = wr * 64 + m * 16 + lr;
        af[m] = *(const short8*)((const char*)As +
                 ((rA * 128 + (kk * 4 + lg) * 16) ^ ((rA & 7) << 4)));
      }
#pragma unroll
      for (int n = 0; n < 4; ++n) {
        int rB = wc * 64 + n * 16 + lr;
        bf[n] = *(const short8*)((const char*)Bs +
                 ((rB * 128 + (kk * 4 + lg) * 16) ^ ((rB & 7) << 4)));
      }
#pragma unroll
      for (int m = 0; m < 4; ++m)
#pragma unroll
        for (int n = 0; n < 4; ++n)
          acc[m][n] = __builtin_amdgcn_mfma_f32_16x16x32_bf16(af[m], bf[n], acc[m][n], 0, 0, 0);
    }
  }

  if (OUT_BF16) {
    unsigned short* C = (unsigned short*)Cout;
#pragma unroll
    for (int m = 0; m < 4; ++m)
#pragma unroll
      for (int n = 0; n < 4; ++n)
#pragma unroll
        for (int r = 0; r < 4; ++r)
          C[(size_t)(row0 + wr * 64 + m * 16 + 4 * lg + r) * N + col0 + wc * 64 + n * 16 + lr] =
              f2bf(acc[m][n][r]);
  } else {
    float* C = (float*)Cout;
#pragma unroll
    for (int m = 0; m < 4; ++m)
#pragma unroll
      for (int n = 0; n < 4; ++n)
#pragma unroll
        for (int r = 0; r < 4; ++r)
          C[(size_t)(row0 + wr * 64 + m * 16 + 4 * lg + r) * N + col0 + wc * 64 + n * 16 + lr] =
              acc[m][n][r];
  }
}

// ---------------- per-head RMSNorm + RoPE (in-place on bf16 qkv) ----------------
// one wave per head-row; 24 head-rows (16 q + 8 k) per (b,s) token.
__global__ __launch_bounds__(256) void k_normrope(unsigned short* __restrict__ qkv,
                                                  const int* __restrict__ pos,
                                                  const float* __restrict__ qw,
                                                  const float* __restrict__ kw) {
  int lane = threadIdx.x & 63;
  int wv = (blockIdx.x << 2) + (threadIdx.x >> 6);
  int bs = wv / 24, hr = wv - bs * 24;
  bool isq = hr < 16;
  int col0 = isq ? hr * 128 : 2048 + (hr - 16) * 128;
  unsigned short* row = qkv + (size_t)bs * QKV_N + col0;
  float x1 = bf2f(row[lane]), x2 = bf2f(row[lane + 64]);
  float ss = x1 * x1 + x2 * x2;
#pragma unroll
  for (int m = 1; m < 64; m <<= 1) ss += __shfl_xor(ss, m, 64);
  float rn = rsqrtf(ss * (1.0f / 128.0f) + 1e-6f);
  const float* w = isq ? qw : kw;
  x1 *= rn * w[lane];
  x2 *= rn * w[lane + 64];
  float p = (float)pos[bs];
  // inv_freq = 10000^(-lane/64) = exp2(-lane * log2(10000)/64)
  float freq = exp2f(-(float)lane * 0.20762050593045951f);
  float ang = p * freq;
  float sn = sinf(ang), cs = cosf(ang);
  float o1 = x1 * cs - x2 * sn;
  float o2 = x2 * cs + x1 * sn;
  float sc = isq ? SCALE_Q : 1.0f;
  row[lane] = f2bf(o1 * sc);
  row[lane + 64] = f2bf(o2 * sc);
}

// ---------------- flash attention (non-causal, GQA rep=2) ----------------
// grid (S/64, B*NH); 4 waves, each owns 16 q-rows. KVBLK=64.
__global__ __launch_bounds__(256) void k_attn(const unsigned short* __restrict__ qkv,
                                              unsigned short* __restrict__ ctx) {
  const int lane = threadIdx.x & 63;
  const int wid = threadIdx.x >> 6;
  const int lr = lane & 15, lg = lane >> 4;
  const int qb = blockIdx.x;
  const int bh = blockIdx.y;
  const int b = bh >> 4, h = bh & 15, kvh = h >> 1;

  __shared__ __align__(16) unsigned short Ks[64 * 128];   // XOR-swizzled rows
  __shared__ __align__(16) unsigned short Vt[128 * 72];   // V^T [d][key], padded
  __shared__ __align__(16) unsigned short Ps[4][16 * 72]; // per-wave P [q][key], padded

  const size_t baseRow = (size_t)b * S_LEN;
  const unsigned short* Qg = qkv + (baseRow + qb * 64 + wid * 16) * QKV_N + h * 128;
  short8 qf[4];
#pragma unroll
  for (int kk = 0; kk < 4; ++kk)
    qf[kk] = *(const short8*)(Qg + (size_t)lr * QKV_N + kk * 32 + lg * 8);

  f32x4 acc[8];
#pragma unroll
  for (int i = 0; i < 8; ++i) acc[i] = (f32x4){0.f, 0.f, 0.f, 0.f};
  float mr[4] = {-1e30f, -1e30f, -1e30f, -1e30f};
  float lrow[4] = {0.f, 0.f, 0.f, 0.f};

  const unsigned short* Kg = qkv + baseRow * QKV_N + 2048 + kvh * 128;
  const unsigned short* Vg = Kg + 1024;

  for (int t = 0; t < 32; ++t) {
    __syncthreads();
    // stage K tile (coalesced global; swizzled LDS write)
#pragma unroll
    for (int i = 0; i < 4; ++i) {
      int c = threadIdx.x + i * 256;
      int row = c >> 4, sub = c & 15;
      short8 v = *(const short8*)(Kg + (size_t)(t * 64 + row) * QKV_N + sub * 8);
      *(short8*)((char*)Ks + ((row * 256 + sub * 16) ^ ((row & 7) << 4))) = v;
    }
    // stage V transposed (LDS-write-spread ordering)
#pragma unroll
    for (int i = 0; i < 4; ++i) {
      int c = threadIdx.x + i * 256;
      int key = c & 63, cc = c >> 6;
      short8 v = *(const short8*)(Vg + (size_t)(t * 64 + key) * QKV_N + cc * 8);
#pragma unroll
      for (int j = 0; j < 8; ++j) Vt[(cc * 8 + j) * 72 + key] = (unsigned short)v[j];
    }
    __syncthreads();

    // QK^T: 16 q-rows x 64 keys
    f32x4 sc[4];
#pragma unroll
    for (int n = 0; n < 4; ++n) sc[n] = (f32x4){0.f, 0.f, 0.f, 0.f};
#pragma unroll
    for (int kk = 0; kk < 4; ++kk) {
#pragma unroll
      for (int n = 0; n < 4; ++n) {
        int key = n * 16 + lr;
        short8 kf = *(const short8*)((const char*)Ks +
                    ((key * 256 + (kk * 4 + lg) * 16) ^ ((key & 7) << 4)));
        sc[n] = __builtin_amdgcn_mfma_f32_16x16x32_bf16(qf[kk], kf, sc[n], 0, 0, 0);
      }
    }

    // online softmax per q-row (16-lane groups hold rows 4*lg..4*lg+3)
#pragma unroll
    for (int r = 0; r < 4; ++r) {
      float mx = fmaxf(fmaxf(sc[0][r], sc[1][r]), fmaxf(sc[2][r], sc[3][r]));
#pragma unroll
      for (int m = 1; m < 16; m <<= 1) mx = fmaxf(mx, __shfl_xor(mx, m, 64));
      float mnew = fmaxf(mr[r], mx);
      float corr = __expf(mr[r] - mnew);
      mr[r] = mnew;
      float ps = 0.f;
#pragma unroll
      for (int n = 0; n < 4; ++n) {
        float p = __expf(sc[n][r] - mnew);
        sc[n][r] = p;
        ps += p;
      }
#pragma unroll
      for (int m = 1; m < 16; m <<= 1) ps += __shfl_xor(ps, m, 64);
      lrow[r] = lrow[r] * corr + ps;
#pragma unroll
      for (int d = 0; d < 8; ++d) acc[d][r] *= corr;
    }

    // P -> LDS (transpose to A-fragment layout), same-wave region: no barrier needed
#pragma unroll
    for (int n = 0; n < 4; ++n)
#pragma unroll
      for (int r = 0; r < 4; ++r)
        Ps[wid][(4 * lg + r) * 72 + n * 16 + lr] = f2bf(sc[n][r]);

    // PV
#pragma unroll
    for (int kk = 0; kk < 2; ++kk) {
      short8 pf = *(const short8*)(&Ps[wid][lr * 72 + kk * 32 + lg * 8]);
#pragma unroll
      for (int d = 0; d < 8; ++d) {
        short8 vf = *(const short8*)(&Vt[(d * 16 + lr) * 72 + kk * 32 + lg * 8]);
        acc[d] = __builtin_amdgcn_mfma_f32_16x16x32_bf16(pf, vf, acc[d], 0, 0, 0);
      }
    }
  }

  unsigned short* Co = ctx + (baseRow + qb * 64 + wid * 16) * 2048 + h * 128;
#pragma unroll
  for (int d = 0; d < 8; ++d)
#pragma unroll
    for (int r = 0; r < 4; ++r)
      Co[(size_t)(4 * lg + r) * 2048 + d * 16 + lr] = f2bf(acc[d][r] / lrow[r]);
}

extern "C" void kernel_launch(void* const* d_in, const int* in_sizes, int n_in,
                              void* d_out, int out_size, void* d_ws, size_t ws_size,
                              hipStream_t stream) {
  const int* positions = (const int*)d_in[0];
  const float* hidden = (const float*)d_in[1];
  const float* w_qkv = (const float*)d_in[2];
  const float* q_norm_w = (const float*)d_in[3];
  const float* k_norm_w = (const float*)d_in[4];
  const float* w_o = (const float*)d_in[5];
  float* out = (float*)d_out;

  char* ws = (char*)d_ws;
  unsigned short* hA    = (unsigned short*)(ws);              // 8192x2048 bf16 (33.5MB), reused as ctx
  unsigned short* wqkvT = (unsigned short*)(ws + 33554432);   // 4096x2048 bf16
  unsigned short* woT   = (unsigned short*)(ws + 50331648);   // 2048x2048 bf16
  unsigned short* qkv   = (unsigned short*)(ws + 58720256);   // 8192x4096 bf16
  unsigned short* ctx   = hA;

  // 1. hidden f32 -> bf16
  k_cvt<<<16384, 256, 0, stream>>>(hidden, hA, (8192 * 2048) / 4);
  // 2. w_qkv [2048][4096] -> [4096][2048] bf16
  k_transpose_cvt<<<dim3(64, 32), 256, 0, stream>>>(w_qkv, wqkvT, 2048, 4096);
  // 3. w_o [2048][2048] -> transposed bf16
  k_transpose_cvt<<<dim3(32, 32), 256, 0, stream>>>(w_o, woT, 2048, 2048);
  // 4. qkv = hidden @ w_qkv   (M=8192, N=4096, K=2048), bf16 out
  k_gemm<1><<<dim3(32, 64), 256, 0, stream>>>(hA, wqkvT, qkv, 8192, 4096, 2048);
  // 5. RMSNorm + RoPE in place (q scaled by HD^-0.5)
  k_normrope<<<49152, 256, 0, stream>>>(qkv, positions, q_norm_w, k_norm_w);
  // 6. attention -> ctx bf16 [8192][2048]
  k_attn<<<dim3(32, 64), 256, 0, stream>>>(qkv, ctx);
  // 7. out = ctx @ w_o (M=8192, N=2048, K=2048), f32 out
  k_gemm<0><<<dim3(16, 64), 256, 0, stream>>>(ctx, woT, out, 8192, 2048, 2048);
}

// Round 2
// 481.472 us; speedup vs baseline: 1.3978x; 1.3978x over previous
//
#include <hip/hip_runtime.h>

#define S_LEN 2048
#define QKV_N 4096
#define SCALE_Q 0.08838834764831845f

typedef __attribute__((ext_vector_type(8))) short short8;
typedef __attribute__((ext_vector_type(4))) float f32x4;
typedef __attribute__((ext_vector_type(16))) float f32x16;
typedef __attribute__((ext_vector_type(4))) float floatv4;
typedef __attribute__((ext_vector_type(4))) unsigned short ushortv4;
typedef __attribute__((ext_vector_type(2))) unsigned int uint2v;

__device__ __forceinline__ float bf2f(unsigned short u) {
  union { unsigned u; float f; } x; x.u = ((unsigned)u) << 16; return x.f;
}
__device__ __forceinline__ unsigned short f2bf(float f) {
  union { float f; unsigned u; } x; x.f = f;
  unsigned r = x.u + 0x7fffu + ((x.u >> 16) & 1u);
  return (unsigned short)(r >> 16);
}

typedef const unsigned int __attribute__((address_space(1)))* gas1_t;
typedef unsigned int __attribute__((address_space(3)))* las3_t;
#define GLL16(g, l) __builtin_amdgcn_global_load_lds((gas1_t)(const void*)(g), (las3_t)(void*)(l), 16, 0, 0)

// ---------------- f32 -> bf16 convert (vectorized) ----------------
__global__ __launch_bounds__(256) void k_cvt(const float* __restrict__ in,
                                             unsigned short* __restrict__ out, int n4) {
  int i = blockIdx.x * 256 + threadIdx.x;
  if (i >= n4) return;
  floatv4 v = ((const floatv4*)in)[i];
  ushortv4 o;
  o[0] = f2bf(v[0]); o[1] = f2bf(v[1]); o[2] = f2bf(v[2]); o[3] = f2bf(v[3]);
  ((ushortv4*)out)[i] = o;
}

// ---------------- transpose + convert: in[R][C] f32 -> out[C][R] bf16 ----------------
__global__ __launch_bounds__(256) void k_transpose_cvt(const float* __restrict__ in,
                                                       unsigned short* __restrict__ out,
                                                       int R, int C) {
  __shared__ float t[64][65];
  int bx = blockIdx.x;
  int by = blockIdx.y;
#pragma unroll
  for (int i = 0; i < 16; ++i) {
    int idx = threadIdx.x + i * 256;
    int r = idx >> 6, c = idx & 63;
    t[r][c] = in[(size_t)(by * 64 + r) * C + bx * 64 + c];
  }
  __syncthreads();
#pragma unroll
  for (int i = 0; i < 16; ++i) {
    int idx = threadIdx.x + i * 256;
    int r = idx >> 6, c = idx & 63;
    out[(size_t)(bx * 64 + r) * R + by * 64 + c] = f2bf(t[c][r]);
  }
}

// ---------------- 128x128x(BK=64) bf16 GEMM, C = A * BT^T ----------------
template <int OUT_BF16>
__global__ __launch_bounds__(256) void k_gemm(const unsigned short* __restrict__ A,
                                              const unsigned short* __restrict__ BT,
                                              void* __restrict__ Cout,
                                              int M, int N, int K) {
  const int lane = threadIdx.x & 63;
  const int wid = threadIdx.x >> 6;
  const int wr = wid >> 1, wc = wid & 1;
  const int lr = lane & 15, lg = lane >> 4;
  const int row0 = blockIdx.y * 128, col0 = blockIdx.x * 128;

  __shared__ __align__(16) unsigned short As[128 * 64];
  __shared__ __align__(16) unsigned short Bs[128 * 64];

  f32x4 acc[4][4];
#pragma unroll
  for (int m = 0; m < 4; ++m)
#pragma unroll
    for (int n = 0; n < 4; ++n) acc[m][n] = (f32x4){0.f, 0.f, 0.f, 0.f};

  size_t aoff[4], boff[4];
  int ldsoff[4];
#pragma unroll
  for (int i = 0; i < 4; ++i) {
    int c = threadIdx.x + i * 256;
    int r = c >> 3, sb = c & 7;
    int cs = (sb ^ (r & 7)) * 8;
    aoff[i] = (size_t)(row0 + r) * K + cs;
    boff[i] = (size_t)(col0 + r) * K + cs;
    ldsoff[i] = c * 16;
  }

  for (int k0 = 0; k0 < K; k0 += 64) {
    __syncthreads();
#pragma unroll
    for (int i = 0; i < 4; ++i) {
      GLL16(A + aoff[i] + k0, (char*)As + ldsoff[i]);
      GLL16(BT + boff[i] + k0, (char*)Bs + ldsoff[i]);
    }
    __syncthreads();
#pragma unroll
    for (int kk = 0; kk < 2; ++kk) {
      short8 af[4], bf[4];
#pragma unroll
      for (int m = 0; m < 4; ++m) {
        int rA = wr * 64 + m * 16 + lr;
        af[m] = *(const short8*)((const char*)As +
                 ((rA * 128 + (kk * 4 + lg) * 16) ^ ((rA & 7) << 4)));
      }
#pragma unroll
      for (int n = 0; n < 4; ++n) {
        int rB = wc * 64 + n * 16 + lr;
        bf[n] = *(const short8*)((const char*)Bs +
                 ((rB * 128 + (kk * 4 + lg) * 16) ^ ((rB & 7) << 4)));
      }
#pragma unroll
      for (int m = 0; m < 4; ++m)
#pragma unroll
        for (int n = 0; n < 4; ++n)
          acc[m][n] = __builtin_amdgcn_mfma_f32_16x16x32_bf16(af[m], bf[n], acc[m][n], 0, 0, 0);
    }
  }

  if (OUT_BF16) {
    unsigned short* C = (unsigned short*)Cout;
#pragma unroll
    for (int m = 0; m < 4; ++m)
#pragma unroll
      for (int n = 0; n < 4; ++n)
#pragma unroll
        for (int r = 0; r < 4; ++r)
          C[(size_t)(row0 + wr * 64 + m * 16 + 4 * lg + r) * N + col0 + wc * 64 + n * 16 + lr] =
              f2bf(acc[m][n][r]);
  } else {
    float* C = (float*)Cout;
#pragma unroll
    for (int m = 0; m < 4; ++m)
#pragma unroll
      for (int n = 0; n < 4; ++n)
#pragma unroll
        for (int r = 0; r < 4; ++r)
          C[(size_t)(row0 + wr * 64 + m * 16 + 4 * lg + r) * N + col0 + wc * 64 + n * 16 + lr] =
              acc[m][n][r];
  }
}

// ---------------- per-head RMSNorm + RoPE (in-place on bf16 qkv) ----------------
__global__ __launch_bounds__(256) void k_normrope(unsigned short* __restrict__ qkv,
                                                  const int* __restrict__ pos,
                                                  const float* __restrict__ qw,
                                                  const float* __restrict__ kw) {
  int lane = threadIdx.x & 63;
  int wv = (blockIdx.x << 2) + (threadIdx.x >> 6);
  int bs = wv / 24, hr = wv - bs * 24;
  bool isq = hr < 16;
  int col0 = isq ? hr * 128 : 2048 + (hr - 16) * 128;
  unsigned short* row = qkv + (size_t)bs * QKV_N + col0;
  float x1 = bf2f(row[lane]), x2 = bf2f(row[lane + 64]);
  float ss = x1 * x1 + x2 * x2;
#pragma unroll
  for (int m = 1; m < 64; m <<= 1) ss += __shfl_xor(ss, m, 64);
  float rn = rsqrtf(ss * (1.0f / 128.0f) + 1e-6f);
  const float* w = isq ? qw : kw;
  x1 *= rn * w[lane];
  x2 *= rn * w[lane + 64];
  float p = (float)pos[bs];
  float freq = exp2f(-(float)lane * 0.20762050593045951f);
  float ang = p * freq;
  float sn = sinf(ang), cs = cosf(ang);
  float o1 = x1 * cs - x2 * sn;
  float o2 = x2 * cs + x1 * sn;
  float sc = isq ? SCALE_Q : 1.0f;
  row[lane] = f2bf(o1 * sc);
  row[lane + 64] = f2bf(o2 * sc);
}

// ---------------- flash attention, 8-warp swapped-QK^T structure ----------------
// grid (S/256, B*NH); 8 waves x 32 q-rows. KVBLK=64, 32x32x16 MFMA.
// K in LDS XOR-swizzled; V in LDS as linear [key/4][d/16][4][16] subtiles read
// via ds_read_b64_tr_b16; P stays in registers (swapped operands), O^T accum.
__global__ __launch_bounds__(512, 2) void k_attn(const unsigned short* __restrict__ qkv,
                                                 unsigned short* __restrict__ ctx) {
  const int tid = threadIdx.x;
  const int lane = tid & 63;
  const int wid = tid >> 6;
  const int hi = lane >> 5;
  const int l15 = lane & 15;
  const int q31 = lane & 31;
  const int qb = blockIdx.x, bh = blockIdx.y;
  const int b = bh >> 4, h = bh & 15, kvh = h >> 1;

  __shared__ __align__(16) unsigned short Ks[2][64 * 128];
  __shared__ __align__(16) unsigned short Vs[2][64 * 128];

  const size_t baseRow = (size_t)b * S_LEN;
  const int qrow = qb * 256 + wid * 32 + q31;

  // Q fragments: lane holds Q[q=lane&31][(lane>>5)*8 + j] per 16-d chunk
  const unsigned short* Qg = qkv + (baseRow + qrow) * QKV_N + h * 128;
  short8 qf[8];
#pragma unroll
  for (int c = 0; c < 8; ++c)
    qf[c] = *(const short8*)(Qg + c * 16 + hi * 8);

  const unsigned short* Kg = qkv + baseRow * QKV_N + 2048 + kvh * 128;
  const unsigned short* Vg = Kg + 1024;

  // staging source offsets (per-thread, 2 slots each of K and V)
  size_t ksrc[2], vsrc[2];
  unsigned sdst[2];
#pragma unroll
  for (int i = 0; i < 2; ++i) {
    int s = tid + i * 512;
    int krow = s >> 4, kc = s & 15;
    ksrc[i] = (size_t)krow * QKV_N + (size_t)((kc ^ (krow & 7)) * 8);
    int st = s >> 3, in8 = s & 7;
    int vkey = (st >> 3) * 4 + (in8 >> 1);
    int vj = ((st & 7) << 1) | (in8 & 1);
    vsrc[i] = (size_t)vkey * QKV_N + (size_t)(vj * 8);
    sdst[i] = (unsigned)s * 16;
  }

#define STAGE(T, BUF)                                                    \
  {                                                                      \
    size_t toff = (size_t)(T) * 64 * QKV_N;                              \
    GLL16(Kg + toff + ksrc[0], (char*)Ks[BUF] + sdst[0]);                \
    GLL16(Kg + toff + ksrc[1], (char*)Ks[BUF] + sdst[1]);                \
    GLL16(Vg + toff + vsrc[0], (char*)Vs[BUF] + sdst[0]);                \
    GLL16(Vg + toff + vsrc[1], (char*)Vs[BUF] + sdst[1]);                \
  }

  f32x16 acc[4];
#pragma unroll
  for (int d = 0; d < 4; ++d)
#pragma unroll
    for (int r = 0; r < 16; ++r) acc[d][r] = 0.f;
  float m_run = -1e30f, l_run = 0.f;

  const unsigned vbase = (unsigned)(uintptr_t)&Vs[0][0];
  const int sw = (q31 & 7) << 4;

  STAGE(0, 0);

  for (int t = 0; t < 32; ++t) {
    const int cur = t & 1;
    __builtin_amdgcn_s_barrier();          // all waves done reading buf[cur^1]
    __builtin_amdgcn_sched_barrier(0);
    if (t < 31) {
      STAGE(t + 1, cur ^ 1);
      asm volatile("s_waitcnt vmcnt(4)" ::: "memory");
    } else {
      asm volatile("s_waitcnt vmcnt(0)" ::: "memory");
    }
    __builtin_amdgcn_s_barrier();          // buf[cur] ready
    __builtin_amdgcn_sched_barrier(0);

    // ---- QK^T (swapped): p[key][q], lane owns q-row = lane&31 ----
    const char* Kb = (const char*)Ks[cur];
    f32x16 p0, p1;
#pragma unroll
    for (int r = 0; r < 16; ++r) { p0[r] = 0.f; p1[r] = 0.f; }
#pragma unroll
    for (int c = 0; c < 8; ++c) {
      int cb = c * 32 + hi * 16;
      short8 k0 = *(const short8*)(Kb + q31 * 256 + (cb ^ sw));
      short8 k1 = *(const short8*)(Kb + (32 + q31) * 256 + (cb ^ sw));
      p0 = __builtin_amdgcn_mfma_f32_32x32x16_bf16(k0, qf[c], p0, 0, 0, 0);
      p1 = __builtin_amdgcn_mfma_f32_32x32x16_bf16(k1, qf[c], p1, 0, 0, 0);
    }

    // ---- online softmax, fully in-lane (q = lane&31) ----
    float mt = p0[0];
#pragma unroll
    for (int r = 1; r < 16; ++r) mt = fmaxf(mt, p0[r]);
#pragma unroll
    for (int r = 0; r < 16; ++r) mt = fmaxf(mt, p1[r]);
    mt = fmaxf(mt, __shfl_xor(mt, 32, 64));
    if (!__all(mt - m_run <= 8.0f)) {       // defer-max (T13)
      float mnew = fmaxf(m_run, mt);
      float corr = __expf(m_run - mnew);
      l_run *= corr;
#pragma unroll
      for (int d = 0; d < 4; ++d)
#pragma unroll
        for (int r = 0; r < 16; ++r) acc[d][r] *= corr;
      m_run = mnew;
    }
    float s_loc = 0.f;
#pragma unroll
    for (int r = 0; r < 16; ++r) { p0[r] = __expf(p0[r] - m_run); s_loc += p0[r]; }
#pragma unroll
    for (int r = 0; r < 16; ++r) { p1[r] = __expf(p1[r] - m_run); s_loc += p1[r]; }
    l_run += s_loc + __shfl_xor(s_loc, 32, 64);

    // ---- PV (swapped): acc[d][q] += V^T x P, per 16-key chunk ----
    const unsigned vb = vbase + (unsigned)cur * 16384u;
    const float* pp0 = (const float*)&p0;
    const float* pp1 = (const float*)&p1;
#pragma unroll
    for (int ks = 0; ks < 4; ++ks) {
      const float* pr = ((ks & 2) ? pp1 : pp0) + (ks & 1) * 8;
      unsigned t0, t1, u0, u1;
      asm("v_cvt_pk_bf16_f32 %0, %1, %2" : "=v"(t0) : "v"(pr[0]), "v"(pr[1]));
      asm("v_cvt_pk_bf16_f32 %0, %1, %2" : "=v"(t1) : "v"(pr[2]), "v"(pr[3]));
      asm("v_cvt_pk_bf16_f32 %0, %1, %2" : "=v"(u0) : "v"(pr[4]), "v"(pr[5]));
      asm("v_cvt_pk_bf16_f32 %0, %1, %2" : "=v"(u1) : "v"(pr[6]), "v"(pr[7]));
      unsigned t0s = __shfl_xor(t0, 32, 64), u0s = __shfl_xor(u0, 32, 64);
      unsigned t1s = __shfl_xor(t1, 32, 64), u1s = __shfl_xor(u1, 32, 64);
      unsigned w0 = hi ? u0s : t0;
      unsigned w1 = hi ? u1s : t1;
      unsigned w2 = hi ? u0 : t0s;
      unsigned w3 = hi ? u1 : t1s;
      union { unsigned u[4]; short8 s; } pa;
      pa.u[0] = w0; pa.u[1] = w1; pa.u[2] = w2; pa.u[3] = w3;

      uint2v vr[4][2];
#pragma unroll
      for (int db = 0; db < 4; ++db)
#pragma unroll
        for (int rd = 0; rd < 2; ++rd) {
          int st = (ks * 4 + hi * 2 + rd) * 8 + db * 2 + ((lane >> 4) & 1);
          unsigned a = vb + (unsigned)(st * 128 + l15 * 8);
          asm volatile("ds_read_b64_tr_b16 %0, %1" : "=v"(vr[db][rd]) : "v"(a));
        }
      asm volatile("s_waitcnt lgkmcnt(0)" ::: "memory");
      __builtin_amdgcn_sched_barrier(0);
#pragma unroll
      for (int db = 0; db < 4; ++db) {
        union { uint2v v[2]; short8 s; } vf;
        vf.v[0] = vr[db][0]; vf.v[1] = vr[db][1];
        acc[db] = __builtin_amdgcn_mfma_f32_32x32x16_bf16(vf.s, pa.s, acc[db], 0, 0, 0);
      }
    }
  }

  // ---- epilogue: O^T accum -> ctx[q][d], lane writes its own q-row ----
  float inv = 1.0f / l_run;
  unsigned short* Co = ctx + (baseRow + qrow) * 2048 + h * 128;
#pragma unroll
  for (int db = 0; db < 4; ++db)
#pragma unroll
    for (int g = 0; g < 4; ++g) {
      ushortv4 v;
#pragma unroll
      for (int j = 0; j < 4; ++j) v[j] = f2bf(acc[db][4 * g + j] * inv);
      *(ushortv4*)(Co + db * 32 + g * 8 + hi * 4) = v;
    }
#undef STAGE
}

extern "C" void kernel_launch(void* const* d_in, const int* in_sizes, int n_in,
                              void* d_out, int out_size, void* d_ws, size_t ws_size,
                              hipStream_t stream) {
  const int* positions = (const int*)d_in[0];
  const float* hidden = (const float*)d_in[1];
  const float* w_qkv = (const float*)d_in[2];
  const float* q_norm_w = (const float*)d_in[3];
  const float* k_norm_w = (const float*)d_in[4];
  const float* w_o = (const float*)d_in[5];
  float* out = (float*)d_out;

  char* ws = (char*)d_ws;
  unsigned short* hA    = (unsigned short*)(ws);              // 8192x2048 bf16, reused as ctx
  unsigned short* wqkvT = (unsigned short*)(ws + 33554432);   // 4096x2048 bf16
  unsigned short* woT   = (unsigned short*)(ws + 50331648);   // 2048x2048 bf16
  unsigned short* qkv   = (unsigned short*)(ws + 58720256);   // 8192x4096 bf16
  unsigned short* ctx   = hA;

  k_cvt<<<16384, 256, 0, stream>>>(hidden, hA, (8192 * 2048) / 4);
  k_transpose_cvt<<<dim3(64, 32), 256, 0, stream>>>(w_qkv, wqkvT, 2048, 4096);
  k_transpose_cvt<<<dim3(32, 32), 256, 0, stream>>>(w_o, woT, 2048, 2048);
  k_gemm<1><<<dim3(32, 64), 256, 0, stream>>>(hA, wqkvT, qkv, 8192, 4096, 2048);
  k_normrope<<<49152, 256, 0, stream>>>(qkv, positions, q_norm_w, k_norm_w);
  k_attn<<<dim3(8, 64), 512, 0, stream>>>(qkv, ctx);
  k_gemm<0><<<dim3(16, 64), 256, 0, stream>>>(ctx, woT, out, 8192, 2048, 2048);
}